// Round 3
// baseline (621.651 us; speedup 1.0000x reference)
//
#include <hip/hip_runtime.h>
#include <math.h>

constexpr int F_IN  = 128;
constexpr int F_H   = 16;
constexpr int F_OUT = 2;
constexpr int BN_LOG = 7;                 // 128 nodes per bucket
constexpr int B_N    = 1 << BN_LOG;
constexpr int SRC_BITS = 17;              // N=100000 < 2^17
constexpr unsigned SRC_MASK = (1u << SRC_BITS) - 1;
constexpr int PART_CHUNK = 4096;          // edges per partition block

// ---- per-bucket histogram of dst ----
__global__ void hist_kernel(const int* __restrict__ dst, int E,
                            int* __restrict__ bcnt, int NB) {
    extern __shared__ int lh[];           // NB ints
    for (int i = threadIdx.x; i < NB; i += blockDim.x) lh[i] = 0;
    __syncthreads();
    int stride = gridDim.x * blockDim.x;
    for (int e = blockIdx.x * blockDim.x + threadIdx.x; e < E; e += stride)
        atomicAdd(&lh[dst[e] >> BN_LOG], 1);
    __syncthreads();
    for (int i = threadIdx.x; i < NB; i += blockDim.x)
        if (lh[i]) atomicAdd(&bcnt[i], lh[i]);
}

// ---- exclusive scan of bucket counts (NB <= 1024) ----
__global__ void scan_kernel(const int* __restrict__ bcnt, int* __restrict__ bstart,
                            int* __restrict__ gcur, int NB) {
    __shared__ int sh[1024];
    int t = threadIdx.x;
    int v = (t < NB) ? bcnt[t] : 0;
    sh[t] = v;
    __syncthreads();
    for (int off = 1; off < 1024; off <<= 1) {
        int u = (t >= off) ? sh[t - off] : 0;
        __syncthreads();
        sh[t] += u;
        __syncthreads();
    }
    int ex = sh[t] - v;
    if (t < NB) { bstart[t] = ex; gcur[t] = ex; }
    if (t == NB - 1) bstart[NB] = ex + v;
}

// ---- partition edges into bucket-contiguous packed runs ----
__global__ void partition_kernel(const int* __restrict__ src, const int* __restrict__ dst,
                                 int E, int* __restrict__ gcur,
                                 unsigned* __restrict__ ebuf, int NB) {
    extern __shared__ int lmem[];         // lh[NB] | lbase[NB]
    int* lh = lmem;
    int* lbase = lmem + NB;
    for (int i = threadIdx.x; i < NB; i += blockDim.x) lh[i] = 0;
    __syncthreads();
    int base = blockIdx.x * PART_CHUNK;
    int end = min(base + PART_CHUNK, E);
    for (int e = base + threadIdx.x; e < end; e += blockDim.x)
        atomicAdd(&lh[dst[e] >> BN_LOG], 1);
    __syncthreads();
    for (int i = threadIdx.x; i < NB; i += blockDim.x) {
        int c = lh[i];
        lbase[i] = c ? atomicAdd(&gcur[i], c) : 0;
        lh[i] = 0;                        // reuse as local cursor
    }
    __syncthreads();
    for (int e = base + threadIdx.x; e < end; e += blockDim.x) {
        int d = dst[e];
        int b = d >> BN_LOG;
        int pos = lbase[b] + atomicAdd(&lh[b], 1);
        ebuf[pos] = ((unsigned)(d & (B_N - 1)) << SRC_BITS) | (unsigned)src[e];
    }
}

// ---- per-bucket degree -> dinv (self-loop folded in as +1) ----
__global__ void dinv_kernel(const unsigned* __restrict__ ebuf, const int* __restrict__ bstart,
                            float* __restrict__ dinv, int N) {
    __shared__ int ldeg[B_N];
    int b = blockIdx.x;
    if (threadIdx.x < B_N) ldeg[threadIdx.x] = 0;
    __syncthreads();
    int s0 = bstart[b], s1 = bstart[b + 1];
    for (int i = s0 + threadIdx.x; i < s1; i += blockDim.x)
        atomicAdd(&ldeg[ebuf[i] >> SRC_BITS], 1);
    __syncthreads();
    int node = b * B_N + threadIdx.x;
    if (threadIdx.x < B_N && node < N)
        dinv[node] = 1.0f / sqrtf((float)(ldeg[threadIdx.x] + 1));
}

// ---- h1 = x @ W1 (one thread per node row, W1 in LDS) ----
__global__ void gemm1_kernel(const float* __restrict__ x, const float* __restrict__ W1,
                             float* __restrict__ h1, int N) {
    __shared__ float w[F_IN * F_H];       // 8 KB
    for (int t = threadIdx.x; t < F_IN * F_H; t += blockDim.x) w[t] = W1[t];
    __syncthreads();
    int row = blockIdx.x * blockDim.x + threadIdx.x;
    if (row >= N) return;
    float acc[F_H];
#pragma unroll
    for (int j = 0; j < F_H; ++j) acc[j] = 0.0f;
    const float4* xr = (const float4*)(x + (size_t)row * F_IN);
#pragma unroll 4
    for (int k4 = 0; k4 < F_IN / 4; ++k4) {
        float4 v = xr[k4];
        const float* wr = &w[k4 * 4 * F_H];
#pragma unroll
        for (int j = 0; j < F_H; ++j)
            acc[j] += v.x * wr[j] + v.y * wr[F_H + j] + v.z * wr[2 * F_H + j] + v.w * wr[3 * F_H + j];
    }
    float4* hr = (float4*)(h1 + (size_t)row * F_H);
    hr[0] = make_float4(acc[0],  acc[1],  acc[2],  acc[3]);
    hr[1] = make_float4(acc[4],  acc[5],  acc[6],  acc[7]);
    hr[2] = make_float4(acc[8],  acc[9],  acc[10], acc[11]);
    hr[3] = make_float4(acc[12], acc[13], acc[14], acc[15]);
}

// ---- layer-1 aggregation into LDS + fused epilogue (bias,ReLU,W2,out init) ----
__global__ void agg1_kernel(const unsigned* __restrict__ ebuf, const int* __restrict__ bstart,
                            const float* __restrict__ dinv, const float* __restrict__ h1,
                            const float* __restrict__ b1, const float* __restrict__ W2,
                            const float* __restrict__ b2,
                            float* __restrict__ h2, float* __restrict__ out, int N) {
    __shared__ float sacc[B_N * F_H];     // 8 KB
    int b = blockIdx.x;
    for (int i = threadIdx.x; i < B_N * F_H; i += blockDim.x) sacc[i] = 0.0f;
    __syncthreads();
    int s0 = bstart[b], s1 = bstart[b + 1];
    int lane = threadIdx.x & 15;
    int grp  = threadIdx.x >> 4;          // 16 groups of 16 lanes
    for (int k0 = s0 + grp * 16; k0 < s1; k0 += 256) {
        int nv = min(16, s1 - k0);
        unsigned p = 0; float dv = 0.0f;
        if (lane < nv) { p = ebuf[k0 + lane]; dv = dinv[p & SRC_MASK]; }
        for (int j = 0; j < nv; ++j) {
            unsigned pj = __shfl(p, j, 16);
            float wj = __shfl(dv, j, 16);
            int s = (int)(pj & SRC_MASK);
            int l = (int)(pj >> SRC_BITS);
            atomicAdd(&sacc[l * F_H + lane], h1[(size_t)s * F_H + lane] * wj);
        }
    }
    __syncthreads();
    int t = threadIdx.x;
    int node = b * B_N + t;
    if (t < B_N && node < N) {
        float di = dinv[node];
        float di2 = di * di;
        float o0 = 0.0f, o1 = 0.0f;
#pragma unroll
        for (int j = 0; j < F_H; ++j) {
            float y = sacc[t * F_H + j] * di + h1[(size_t)node * F_H + j] * di2 + b1[j];
            y = fmaxf(y, 0.0f);
            o0 += y * W2[j * F_OUT + 0];
            o1 += y * W2[j * F_OUT + 1];
        }
        ((float2*)h2)[node] = make_float2(o0, o1);
        ((float2*)out)[node] = make_float2(b2[0] + o0 * di2, b2[1] + o1 * di2);
    }
}

// ---- layer-2 aggregation into LDS ----
__global__ void agg2_kernel(const unsigned* __restrict__ ebuf, const int* __restrict__ bstart,
                            const float* __restrict__ dinv, const float* __restrict__ h2,
                            float* __restrict__ out, int N) {
    __shared__ float sa0[B_N], sa1[B_N];
    int b = blockIdx.x;
    int t = threadIdx.x;
    if (t < B_N) { sa0[t] = 0.0f; sa1[t] = 0.0f; }
    __syncthreads();
    int s0 = bstart[b], s1 = bstart[b + 1];
    for (int i = s0 + t; i < s1; i += blockDim.x) {
        unsigned p = ebuf[i];
        int s = (int)(p & SRC_MASK);
        int l = (int)(p >> SRC_BITS);
        float w = dinv[s];
        float2 v = ((const float2*)h2)[s];
        atomicAdd(&sa0[l], v.x * w);
        atomicAdd(&sa1[l], v.y * w);
    }
    __syncthreads();
    int node = b * B_N + t;
    if (t < B_N && node < N) {
        float di = dinv[node];
        float2 o = ((float2*)out)[node];
        o.x += sa0[t] * di;
        o.y += sa1[t] * di;
        ((float2*)out)[node] = o;
    }
}

// ================= launch =================

extern "C" void kernel_launch(void* const* d_in, const int* in_sizes, int n_in,
                              void* d_out, int out_size, void* d_ws, size_t ws_size,
                              hipStream_t stream) {
    const float* x  = (const float*)d_in[0];
    const int*   ei = (const int*)d_in[1];
    const float* W1 = (const float*)d_in[2];
    const float* b1 = (const float*)d_in[3];
    const float* W2 = (const float*)d_in[4];
    const float* b2 = (const float*)d_in[5];
    float* out = (float*)d_out;

    const int N = out_size / F_OUT;       // 100000
    const int E = in_sizes[1] / 2;        // 3200000
    const int* srcp = ei;
    const int* dstp = ei + E;
    const int NB = (N + B_N - 1) / B_N;   // 782

    // workspace layout (256B-aligned chunks):
    // h1[16N] f32 | ebuf[E] u32 | h2[2N] f32 | dinv[N] f32 | bcnt[NB] | bstart[NB+1] | gcur[NB]
    auto align = [](size_t v) { return (v + 255) & ~(size_t)255; };
    char* ws = (char*)d_ws;
    size_t off = 0;
    float*    h1    = (float*)(ws + off); off = align(off + (size_t)N * F_H * 4);
    unsigned* ebuf  = (unsigned*)(ws + off); off = align(off + (size_t)E * 4);
    float*    h2    = (float*)(ws + off); off = align(off + (size_t)N * F_OUT * 4);
    float*    dinv  = (float*)(ws + off); off = align(off + (size_t)N * 4);
    int*      bcnt  = (int*)(ws + off); off = align(off + (size_t)NB * 4);
    int*      bstart= (int*)(ws + off); off = align(off + (size_t)(NB + 1) * 4);
    int*      gcur  = (int*)(ws + off); off = align(off + (size_t)NB * 4);

    const int npart = (E + PART_CHUNK - 1) / PART_CHUNK;

    hipMemsetAsync(bcnt, 0, (size_t)NB * 4, stream);
    hist_kernel<<<npart, 256, NB * 4, stream>>>(dstp, E, bcnt, NB);
    scan_kernel<<<1, 1024, 0, stream>>>(bcnt, bstart, gcur, NB);
    partition_kernel<<<npart, 256, 2 * NB * 4, stream>>>(srcp, dstp, E, gcur, ebuf, NB);
    gemm1_kernel<<<(N + 255) / 256, 256, 0, stream>>>(x, W1, h1, N);
    dinv_kernel<<<NB, 256, 0, stream>>>(ebuf, bstart, dinv, N);
    agg1_kernel<<<NB, 256, 0, stream>>>(ebuf, bstart, dinv, h1, b1, W2, b2, h2, out, N);
    agg2_kernel<<<NB, 256, 0, stream>>>(ebuf, bstart, dinv, h2, out, N);
}

// Round 4
// 583.800 us; speedup vs baseline: 1.0648x; 1.0648x over previous
//
#include <hip/hip_runtime.h>
#include <math.h>

constexpr int F_IN  = 128;
constexpr int F_H   = 16;
constexpr int F_OUT = 2;
constexpr int BN_LOG = 7;                 // 128 nodes per bucket
constexpr int B_N    = 1 << BN_LOG;
constexpr int SRC_BITS = 17;              // N=100000 < 2^17
constexpr unsigned SRC_MASK = (1u << SRC_BITS) - 1;
constexpr int PART_CHUNK = 4096;          // edges per partition block

// ---- per-bucket histogram of dst ----
__global__ void hist_kernel(const int* __restrict__ dst, int E,
                            int* __restrict__ bcnt, int NB) {
    extern __shared__ int lh[];           // NB ints
    for (int i = threadIdx.x; i < NB; i += blockDim.x) lh[i] = 0;
    __syncthreads();
    int base = blockIdx.x * PART_CHUNK;
    int end = min(base + PART_CHUNK, E);
    for (int e = base + threadIdx.x; e < end; e += blockDim.x)
        atomicAdd(&lh[dst[e] >> BN_LOG], 1);
    __syncthreads();
    for (int i = threadIdx.x; i < NB; i += blockDim.x)
        if (lh[i]) atomicAdd(&bcnt[i], lh[i]);
}

// ---- exclusive scan of bucket counts (NB <= 1024) ----
__global__ void scan_kernel(const int* __restrict__ bcnt, int* __restrict__ bstart,
                            int* __restrict__ gcur, int NB) {
    __shared__ int sh[1024];
    int t = threadIdx.x;
    int v = (t < NB) ? bcnt[t] : 0;
    sh[t] = v;
    __syncthreads();
    for (int off = 1; off < 1024; off <<= 1) {
        int u = (t >= off) ? sh[t - off] : 0;
        __syncthreads();
        sh[t] += u;
        __syncthreads();
    }
    int ex = sh[t] - v;
    if (t < NB) { bstart[t] = ex; gcur[t] = ex; }
    if (t == NB - 1) bstart[NB] = ex + v;
}

// ---- partition edges into bucket-contiguous packed runs ----
__global__ void partition_kernel(const int* __restrict__ src, const int* __restrict__ dst,
                                 int E, int* __restrict__ gcur,
                                 unsigned* __restrict__ ebuf, int NB) {
    extern __shared__ int lmem[];         // lh[NB] | lbase[NB]
    int* lh = lmem;
    int* lbase = lmem + NB;
    for (int i = threadIdx.x; i < NB; i += blockDim.x) lh[i] = 0;
    __syncthreads();
    int base = blockIdx.x * PART_CHUNK;
    int end = min(base + PART_CHUNK, E);
    for (int e = base + threadIdx.x; e < end; e += blockDim.x)
        atomicAdd(&lh[dst[e] >> BN_LOG], 1);
    __syncthreads();
    for (int i = threadIdx.x; i < NB; i += blockDim.x) {
        int c = lh[i];
        lbase[i] = c ? atomicAdd(&gcur[i], c) : 0;
        lh[i] = 0;                        // reuse as local cursor
    }
    __syncthreads();
    for (int e = base + threadIdx.x; e < end; e += blockDim.x) {
        int d = dst[e];
        int b = d >> BN_LOG;
        int pos = lbase[b] + atomicAdd(&lh[b], 1);
        ebuf[pos] = ((unsigned)(d & (B_N - 1)) << SRC_BITS) | (unsigned)src[e];
    }
}

// ---- per-bucket degree -> dinv (self-loop folded in as +1) ----
__global__ void dinv_kernel(const unsigned* __restrict__ ebuf, const int* __restrict__ bstart,
                            float* __restrict__ dinv, int N) {
    __shared__ int ldeg[B_N];
    int b = blockIdx.x;
    if (threadIdx.x < B_N) ldeg[threadIdx.x] = 0;
    __syncthreads();
    int s0 = bstart[b], s1 = bstart[b + 1];
    for (int i = s0 + threadIdx.x; i < s1; i += blockDim.x)
        atomicAdd(&ldeg[ebuf[i] >> SRC_BITS], 1);
    __syncthreads();
    int node = b * B_N + threadIdx.x;
    if (threadIdx.x < B_N && node < N)
        dinv[node] = 1.0f / sqrtf((float)(ldeg[threadIdx.x] + 1));
}

// ---- h1s = (x @ W1) * dinv[row]  (pre-scaled by src-side norm) ----
__global__ void gemm1_kernel(const float* __restrict__ x, const float* __restrict__ W1,
                             const float* __restrict__ dinv, float* __restrict__ h1s, int N) {
    __shared__ float w[F_IN * F_H];       // 8 KB
    for (int t = threadIdx.x; t < F_IN * F_H; t += blockDim.x) w[t] = W1[t];
    __syncthreads();
    int row = blockIdx.x * blockDim.x + threadIdx.x;
    if (row >= N) return;
    float acc[F_H];
#pragma unroll
    for (int j = 0; j < F_H; ++j) acc[j] = 0.0f;
    const float4* xr = (const float4*)(x + (size_t)row * F_IN);
#pragma unroll 4
    for (int k4 = 0; k4 < F_IN / 4; ++k4) {
        float4 v = xr[k4];
        const float* wr = &w[k4 * 4 * F_H];
#pragma unroll
        for (int j = 0; j < F_H; ++j)
            acc[j] += v.x * wr[j] + v.y * wr[F_H + j] + v.z * wr[2 * F_H + j] + v.w * wr[3 * F_H + j];
    }
    float di = dinv[row];
    float4* hr = (float4*)(h1s + (size_t)row * F_H);
    hr[0] = make_float4(acc[0] * di,  acc[1] * di,  acc[2] * di,  acc[3] * di);
    hr[1] = make_float4(acc[4] * di,  acc[5] * di,  acc[6] * di,  acc[7] * di);
    hr[2] = make_float4(acc[8] * di,  acc[9] * di,  acc[10] * di, acc[11] * di);
    hr[3] = make_float4(acc[12] * di, acc[13] * di, acc[14] * di, acc[15] * di);
}

// ---- layer-1 aggregation: one THREAD per edge, LDS feature-major accumulate ----
// fused epilogue: y = (acc + selfloop)*dinv + b1; ReLU; o = y@W2; h2s = o*dinv; out init.
__global__ void __launch_bounds__(512)
agg1_kernel(const unsigned* __restrict__ ebuf, const int* __restrict__ bstart,
            const float* __restrict__ dinv, const float* __restrict__ h1s,
            const float* __restrict__ b1, const float* __restrict__ W2,
            const float* __restrict__ b2,
            float* __restrict__ h2s, float* __restrict__ out, int N) {
    __shared__ float sacc[F_H][B_N];      // feature-major: bank = l%32, random -> ~2-way
    int b = blockIdx.x;
    for (int i = threadIdx.x; i < F_H * B_N; i += blockDim.x)
        ((float*)sacc)[i] = 0.0f;
    __syncthreads();
    int s0 = bstart[b], s1 = bstart[b + 1];
#pragma unroll 2
    for (int i = s0 + threadIdx.x; i < s1; i += 512) {
        unsigned p = ebuf[i];             // coalesced
        int s = (int)(p & SRC_MASK);
        int l = (int)(p >> SRC_BITS);
        const float4* hr = (const float4*)(h1s + (size_t)s * F_H);
        float4 v0 = hr[0], v1 = hr[1], v2 = hr[2], v3 = hr[3];   // 4 independent line loads
        atomicAdd(&sacc[0][l],  v0.x); atomicAdd(&sacc[1][l],  v0.y);
        atomicAdd(&sacc[2][l],  v0.z); atomicAdd(&sacc[3][l],  v0.w);
        atomicAdd(&sacc[4][l],  v1.x); atomicAdd(&sacc[5][l],  v1.y);
        atomicAdd(&sacc[6][l],  v1.z); atomicAdd(&sacc[7][l],  v1.w);
        atomicAdd(&sacc[8][l],  v2.x); atomicAdd(&sacc[9][l],  v2.y);
        atomicAdd(&sacc[10][l], v2.z); atomicAdd(&sacc[11][l], v2.w);
        atomicAdd(&sacc[12][l], v3.x); atomicAdd(&sacc[13][l], v3.y);
        atomicAdd(&sacc[14][l], v3.z); atomicAdd(&sacc[15][l], v3.w);
    }
    __syncthreads();
    int t = threadIdx.x;
    int node = b * B_N + t;
    if (t < B_N && node < N) {
        float di = dinv[node];
        const float4* hr = (const float4*)(h1s + (size_t)node * F_H);
        float self[F_H];
        ((float4*)self)[0] = hr[0]; ((float4*)self)[1] = hr[1];
        ((float4*)self)[2] = hr[2]; ((float4*)self)[3] = hr[3];
        float o0 = 0.0f, o1 = 0.0f;
#pragma unroll
        for (int j = 0; j < F_H; ++j) {
            float y = (sacc[j][t] + self[j]) * di + b1[j];
            y = fmaxf(y, 0.0f);
            o0 += y * W2[j * F_OUT + 0];
            o1 += y * W2[j * F_OUT + 1];
        }
        ((float2*)h2s)[node] = make_float2(o0 * di, o1 * di);    // pre-scaled for layer 2
        ((float2*)out)[node] = make_float2(b2[0] + o0 * di * di, b2[1] + o1 * di * di);
    }
}

// ---- layer-2 aggregation: one thread per edge ----
__global__ void __launch_bounds__(512)
agg2_kernel(const unsigned* __restrict__ ebuf, const int* __restrict__ bstart,
            const float* __restrict__ dinv, const float* __restrict__ h2s,
            float* __restrict__ out, int N) {
    __shared__ float sa0[B_N], sa1[B_N];
    int b = blockIdx.x;
    int t = threadIdx.x;
    if (t < B_N) { sa0[t] = 0.0f; sa1[t] = 0.0f; }
    __syncthreads();
    int s0 = bstart[b], s1 = bstart[b + 1];
#pragma unroll 2
    for (int i = s0 + t; i < s1; i += 512) {
        unsigned p = ebuf[i];
        int s = (int)(p & SRC_MASK);
        int l = (int)(p >> SRC_BITS);
        float2 v = ((const float2*)h2s)[s];
        atomicAdd(&sa0[l], v.x);
        atomicAdd(&sa1[l], v.y);
    }
    __syncthreads();
    int node = b * B_N + t;
    if (t < B_N && node < N) {
        float di = dinv[node];
        float2 o = ((float2*)out)[node];
        o.x += sa0[t] * di;
        o.y += sa1[t] * di;
        ((float2*)out)[node] = o;
    }
}

// ================= launch =================

extern "C" void kernel_launch(void* const* d_in, const int* in_sizes, int n_in,
                              void* d_out, int out_size, void* d_ws, size_t ws_size,
                              hipStream_t stream) {
    const float* x  = (const float*)d_in[0];
    const int*   ei = (const int*)d_in[1];
    const float* W1 = (const float*)d_in[2];
    const float* b1 = (const float*)d_in[3];
    const float* W2 = (const float*)d_in[4];
    const float* b2 = (const float*)d_in[5];
    float* out = (float*)d_out;

    const int N = out_size / F_OUT;       // 100000
    const int E = in_sizes[1] / 2;        // 3200000
    const int* srcp = ei;
    const int* dstp = ei + E;
    const int NB = (N + B_N - 1) / B_N;   // 782

    auto align = [](size_t v) { return (v + 255) & ~(size_t)255; };
    char* ws = (char*)d_ws;
    size_t off = 0;
    float*    h1s   = (float*)(ws + off); off = align(off + (size_t)N * F_H * 4);
    unsigned* ebuf  = (unsigned*)(ws + off); off = align(off + (size_t)E * 4);
    float*    h2s   = (float*)(ws + off); off = align(off + (size_t)N * F_OUT * 4);
    float*    dinv  = (float*)(ws + off); off = align(off + (size_t)N * 4);
    int*      bcnt  = (int*)(ws + off); off = align(off + (size_t)NB * 4);
    int*      bstart= (int*)(ws + off); off = align(off + (size_t)(NB + 1) * 4);
    int*      gcur  = (int*)(ws + off); off = align(off + (size_t)NB * 4);

    const int npart = (E + PART_CHUNK - 1) / PART_CHUNK;

    hipMemsetAsync(bcnt, 0, (size_t)NB * 4, stream);
    hist_kernel<<<npart, 256, NB * 4, stream>>>(dstp, E, bcnt, NB);
    scan_kernel<<<1, 1024, 0, stream>>>(bcnt, bstart, gcur, NB);
    partition_kernel<<<npart, 256, 2 * NB * 4, stream>>>(srcp, dstp, E, gcur, ebuf, NB);
    dinv_kernel<<<NB, 256, 0, stream>>>(ebuf, bstart, dinv, N);
    gemm1_kernel<<<(N + 255) / 256, 256, 0, stream>>>(x, W1, dinv, h1s, N);
    agg1_kernel<<<NB, 512, 0, stream>>>(ebuf, bstart, dinv, h1s, b1, W2, b2, h2s, out, N);
    agg2_kernel<<<NB, 512, 0, stream>>>(ebuf, bstart, dinv, h2s, out, N);
}